// Round 9
// baseline (2615.076 us; speedup 1.0000x reference)
//
#include <hip/hip_runtime.h>
#include <hip/hip_bf16.h>

typedef unsigned short u16;
typedef unsigned int u32;
typedef unsigned long long u64;
typedef __attribute__((ext_vector_type(8))) short short8;
typedef __attribute__((ext_vector_type(4))) float floatx4;

#define I_DIM 256
#define H_DIM 1024
#define B_DIM 64
#define T_DIM 256
#define C_DIM 60
#define NWG   128
#define UPW   8      // hidden units per WG
#define BSTR  12     // pacc row stride (dwords): 16B-aligned rows, bank-spread
#define PACE  5      // post-publish visibility sleep, units of s_sleep(8)

// LDS layout (bytes)
#define LDS_W_OFF    0        // 2*40*4*16 frags * 16B = 81920
#define LDS_BIAS_OFF 81920    // 32*4 = 128
#define LDS_PACC_OFF 82048    // 8 streams * 2 bufs * 64 rows * 12 dw * 4B = 49152
#define LDS_FLAG_OFF 131200   // 8 ints
#define LDS_TOTAL    131232

// workspace layout (bytes)
#define WS_XSWZ   0u          // T*B*I bf16 = 8388608
#define WS_HSWZ   8388608u    // 256 slots * 64*1024 bf16 = 33554432 (never reused)
#define WS_HLAST  41943040u   // 64*1024 f32 = 262144

#define LSBM 0x0001000100010001ull

__device__ __forceinline__ u16 f2bf(float f) {
    u32 u = __float_as_uint(f);
    u32 r = (u + 0x7fffu + ((u >> 16) & 1u)) >> 16;
    return (u16)r;
}
__device__ __forceinline__ float fsig(float x) { return 1.0f / (1.0f + __expf(-x)); }
__device__ __forceinline__ float ftanh(float x) { return 2.0f * fsig(2.0f * x) - 1.0f; }

union hfrag { short8 s; u64 q[2]; };

// ---------------------------------------------------------------------------
// Pre-swizzle inputs [B][T][I] fp32 -> xswz[t] bf16 in MFMA-A-fragment layout:
// 16B unit index (per t): ((mt*8 + s)*4 + q)*16 + m  holds A[b=mt*16+m][k=s*32+q*8 .. +7]
// ---------------------------------------------------------------------------
extern "C" __global__ void prep_x(const float* __restrict__ in, u16* __restrict__ xswz) {
    int o = blockIdx.x * 256 + threadIdx.x;           // octet index, 524288 total
    int m = o & 15, q = (o >> 4) & 3, s = (o >> 6) & 7, mt = (o >> 9) & 3, t = o >> 11;
    int b = mt * 16 + m, k = s * 32 + q * 8;
    const float* src = in + ((size_t)(b * T_DIM + t)) * I_DIM + k;
    float4 v0 = *(const float4*)src;
    float4 v1 = *(const float4*)(src + 4);
    short8 val;
    val[0] = (short)f2bf(v0.x); val[1] = (short)f2bf(v0.y);
    val[2] = (short)f2bf(v0.z); val[3] = (short)f2bf(v0.w);
    val[4] = (short)f2bf(v1.x); val[5] = (short)f2bf(v1.y);
    val[6] = (short)f2bf(v1.z); val[7] = (short)f2bf(v1.w);
    *(short8*)(xswz + (size_t)o * 8) = val;
}

// ---------------------------------------------------------------------------
// Persistent LSTM scan (r18): EIGHT r16-STREAMS (4-way TLP, r16 structure).
// r16 (4 streams x 2 waves, 2 waves/SIMD) = 865us, the only win; r17's
// restructure (4-wave K-split, double rendezvous, imbalance) regressed.
// r18 scales the PROVEN stream unit: 1024 threads = 16 waves = 8 independent
// streams x 2 waves, one stream per HALF batch-tile (8 batches). w = s*2+ws
// -> each SIMD hosts wave-ws of 4 DISTINCT streams (4-way interleave).
// M-tiles stay 16 rows: sibling batch rows are computed and DISCARDED
// (MFMA pipe is 8% utilized and separate from VALU -- the 2x waste is free).
// Isolation by construction (empirical frag maps from r16: A-batch = m16,
// acc batch = q4*4+reg, unit = m16):
//   - h loads DUPLICATE own half (em = half*8 + (m16&7)): never touches
//     sibling cache lines -> no cross-stream L2 poisoning (r11's storm
//     mode), tags valid on ALL lanes (no masked checks);
//   - C-write keeps own batch half only (cq = q4-2*half in {0,1});
//   - publish/pointwise cover own 8 batches x 8 units (64 items).
// Everything else is r16 verbatim: balanced 4x+16h sg split per wave, ONE
// LDS-atomic rendezvous per step (pacc double-buffered), ack-free tagged 2B
// publish (tag=(t%13)+1 per-u16 lsb, never 0=poison), throttled agent
// repair, PACE visibility sleep (free: 3 co-streams per SIMD issue while
// sleeping), slot-per-step hswz (stale L2 hits structurally impossible).
// ---------------------------------------------------------------------------
extern "C" __global__ void __launch_bounds__(1024, 1) lstm_scan(
    const u16* __restrict__ xswz, u16* hswz,
    const float* __restrict__ Wih, const float* __restrict__ Whh,
    const float* __restrict__ bih, const float* __restrict__ bhh,
    float* hlast)
{
    extern __shared__ char lds[];
    u16*   Wlds = (u16*)(lds + LDS_W_OFF);
    float* bias = (float*)(lds + LDS_BIAS_OFF);
    float* pacc = (float*)(lds + LDS_PACC_OFF);
    int*   sbf  = (int*)(lds + LDS_FLAG_OFF);

    const int j    = blockIdx.x;
    const int tid  = threadIdx.x;
    const int lane = tid & 63;
    const int w    = tid >> 6;    // 0..15
    const int s    = w >> 1;      // stream 0..7
    const int ws   = w & 1;       // wave within stream
    const int mt   = s >> 1;      // batch tile 0..3
    const int half = s & 1;       // half of tile (batches half*8 .. +7)

    // ---- stage W slice into LDS, bf16, B-swizzled:
    // unit wu = ((nt*40 + sg)*4 + q)*16 + nn  holds W[r(nt,nn)][sg*32+q*8 .. +7]
    for (int i = 0; i < 5; ++i) {
        int wu = tid + i * 1024;
        int nn = wu & 15, q = (wu >> 4) & 3, rest = wu >> 6;
        int sg = rest % 40, nt = rest / 40;
        int n = nt * 16 + nn;
        int g = n >> 3, uu = n & 7;
        int r = g * H_DIM + j * UPW + uu;
        int kb = sg * 32 + q * 8;
        const float* src = (kb < I_DIM) ? (Wih + (size_t)r * I_DIM + kb)
                                        : (Whh + (size_t)r * H_DIM + (kb - I_DIM));
        short8 val;
        #pragma unroll
        for (int e = 0; e < 8; ++e) val[e] = (short)f2bf(src[e]);
        *(short8*)(Wlds + (size_t)wu * 8) = val;
    }
    if (tid < 32) {
        int n = tid, g = n >> 3, uu = n & 7;
        int r = g * H_DIM + j * UPW + uu;
        bias[n] = bih[r] + bhh[r];
    }
    if (tid < 8) sbf[tid] = 0;
    __syncthreads();   // last WG-wide barrier in the kernel

    const int m16 = lane & 15, q4 = lane >> 4;
    const int em  = half * 8 + (m16 & 7);     // h-load row, duplicated own half
    const int cq  = q4 - 2 * half;            // C-write col-block; valid 0..1
    const int item  = ws * 32 + (lane & 31);  // pointwise item (lane<32): 64/stream
    const int pw_pm = item >> 3;              // batch-in-8
    const int pw_uu = item & 7;               // hidden unit within WG's 8
    const int pw_m  = half * 8 + pw_pm;       // batch-in-16
    float creg = 0.0f;                        // c state for this lane's item
    float* pc_s = pacc + s * (2 * 64 * BSTR); // stream-private pacc (dbuf)
    int*   flag = sbf + s;

    // A-frags: ss 0..3 = x (sg = ws*4+ss), ss 4..19 = h (sgh = ws*16+ss-4)
    hfrag a[20];

    // ---- prologue: loads for t=0 (slot 0 = h_0 = 0, no tag check at t=0)
    #pragma unroll
    for (int ss = 0; ss < 4; ++ss) {
        int sg = ws * 4 + ss;
        a[ss].s = *(const short8*)(xswz
            + (size_t)(((mt * 8 + sg) * 4 + q4) * 16 + m16) * 8);
    }
    #pragma unroll
    for (int ss = 4; ss < 20; ++ss) {
        int sgh = ws * 16 + (ss - 4);
        a[ss].s = *(const short8*)(hswz
            + (size_t)(((mt * 32 + sgh) * 4 + q4) * 16 + em) * 8);
    }

    for (int t = 0; t < T_DIM; ++t) {
        const u16* hbase = hswz + (size_t)t * (B_DIM * H_DIM);   // fresh slot
        u16*       hnext = hswz + (size_t)(t + 1) * (B_DIM * H_DIM);
        const u16* xnext = xswz + (size_t)(t + 1) * (B_DIM * I_DIM);
        const int  En    = (t % 13) + 1;          // tag nibble, never 0
        const u64  Eq    = (u64)(En & 1) | ((u64)((En >> 1) & 1) << 16)
                         | ((u64)((En >> 2) & 1) << 32) | ((u64)((En >> 3) & 1) << 48);
        const int  Ep    = ((t + 1) % 13) + 1;

        // ---- x part: 8 MFMAs while h loads (in flight) arrive
        floatx4 acc[2];
        acc[0] = (floatx4){0.f, 0.f, 0.f, 0.f};
        acc[1] = (floatx4){0.f, 0.f, 0.f, 0.f};
        #pragma unroll
        for (int ss = 0; ss < 4; ++ss) {
            int sg = ws * 4 + ss;
            #pragma unroll
            for (int nt = 0; nt < 2; ++nt) {
                short8 bv = *(const short8*)(Wlds
                    + (size_t)(((nt * 40 + sg) * 4 + q4) * 16 + m16) * 8);
                acc[nt] = __builtin_amdgcn_mfma_f32_16x16x32_bf16(
                    a[ss].s, bv, acc[nt], 0, 0, 0);
            }
        }

        // ---- validate h-frag tags (all lanes hold own-half data thanks to
        // duplication); throttled agent-scope repair of misses only
        if (t > 0) {
            u32 mk = 0;
            #pragma unroll
            for (int ss = 4; ss < 20; ++ss)
                if ((((a[ss].q[0] ^ Eq) | (a[ss].q[1] ^ Eq)) & LSBM) != 0)
                    mk |= 1u << ss;
            int rounds = 0;
            while (__any(mk != 0)) {
                ++rounds;
                #pragma unroll
                for (int ss = 4; ss < 20; ++ss)
                    if ((mk >> ss) & 1) {
                        int sgh = ws * 16 + (ss - 4);
                        const u64* pp = (const u64*)hbase
                            + (size_t)(((mt * 32 + sgh) * 4 + q4) * 16 + em) * 2;
                        a[ss].q[0] = __hip_atomic_load(pp,     __ATOMIC_RELAXED, __HIP_MEMORY_SCOPE_AGENT);
                        a[ss].q[1] = __hip_atomic_load(pp + 1, __ATOMIC_RELAXED, __HIP_MEMORY_SCOPE_AGENT);
                    }
                #pragma unroll
                for (int ss = 4; ss < 20; ++ss)
                    if (((mk >> ss) & 1) &&
                        ((((a[ss].q[0] ^ Eq) | (a[ss].q[1] ^ Eq)) & LSBM) == 0))
                        mk &= ~(1u << ss);
                if (__any(mk != 0)) {
                    if (rounds < 4) __builtin_amdgcn_s_sleep(4);
                    else            __builtin_amdgcn_s_sleep(16);
                }
            }
        }

        // ---- h part: 32 MFMAs (16 h-sg x 2 ntiles)
        #pragma unroll
        for (int ss = 4; ss < 20; ++ss) {
            int sg = 8 + ws * 16 + (ss - 4);
            #pragma unroll
            for (int nt = 0; nt < 2; ++nt) {
                short8 bv = *(const short8*)(Wlds
                    + (size_t)(((nt * 40 + sg) * 4 + q4) * 16 + m16) * 8);
                acc[nt] = __builtin_amdgcn_mfma_f32_16x16x32_bf16(
                    a[ss].s, bv, acc[nt], 0, 0, 0);
            }
        }

        // ---- K-partials to stream-private pacc[t&1], OWN batch half only:
        // acc batch = q4*4+reg, unit = m16. row = ws*32 + nt*16 + m16.
        float* pc = pc_s + (t & 1) * (64 * BSTR);
        if (cq >= 0 && cq < 2) {
            #pragma unroll
            for (int nt = 0; nt < 2; ++nt)
                *(floatx4*)(pc + (ws * 32 + nt * 16 + m16) * BSTR + cq * 4) = acc[nt];
        }

        // ---- stream rendezvous (monotonic LDS counter, 2 waves, one phase)
        asm volatile("s_waitcnt lgkmcnt(0)" ::: "memory");
        if (lane == 0)
            __hip_atomic_fetch_add(flag, 1, __ATOMIC_RELAXED,
                                   __HIP_MEMORY_SCOPE_WORKGROUP);
        {
            const int tgt = 2 * (t + 1);
            while (__hip_atomic_load(flag, __ATOMIC_RELAXED,
                                     __HIP_MEMORY_SCOPE_WORKGROUP) < tgt)
                __builtin_amdgcn_s_sleep(1);
        }
        asm volatile("" ::: "memory");

        // ---- pointwise (64 items on lane<32 of both waves): reduce 2 wave-
        // partials, gates, c/h update; direct tagged 2B publish
        if ((lane & 63) < 32) {
            float sv[4];
            #pragma unroll
            for (int g = 0; g < 4; ++g) {
                sv[g] = bias[g * 8 + pw_uu]
                      + pc[(g * 8 + pw_uu) * BSTR + pw_pm]
                      + pc[(32 + g * 8 + pw_uu) * BSTR + pw_pm];
            }
            float ig = fsig(sv[0]), fg = fsig(sv[1]), gg = ftanh(sv[2]), og = fsig(sv[3]);
            float c = fg * creg + ig * gg;
            creg = c;
            float h = og * ftanh(c);
            if (t == T_DIM - 1) {
                hlast[(size_t)(mt * 16 + pw_m) * H_DIM + j * UPW + pw_uu] = h;
            } else {
                u16 hb16 = (u16)((f2bf(h) & 0xFFFEu) | ((u32)(Ep >> (pw_uu & 3)) & 1u));
                // unit octet ((mt*32 + (j>>2))*4 + (j&3))*16 + m, elem uu
                u16* dst = hnext
                    + (size_t)(((mt * 32 + (j >> 2)) * 4 + (j & 3)) * 16 + pw_m) * 8
                    + pw_uu;
                __hip_atomic_store(dst, hb16, __ATOMIC_RELAXED,
                                   __HIP_MEMORY_SCOPE_AGENT);
            }
        }
        asm volatile("" ::: "memory");
        // no second rendezvous: pacc is double-buffered; read(t) precedes
        // flag(t+1) precedes write(t+2) on the same buffer

        // ---- issue next step's loads: x now (tag-free), h after the
        // visibility sleep (sleep is free: 3 co-streams per SIMD issue)
        if (t + 1 < T_DIM) {
            #pragma unroll
            for (int ss = 0; ss < 4; ++ss) {
                int sg = ws * 4 + ss;
                a[ss].s = *(const short8*)(xnext
                    + (size_t)(((mt * 8 + sg) * 4 + q4) * 16 + m16) * 8);
            }
            for (int p = 0; p < PACE; ++p) __builtin_amdgcn_s_sleep(8);
            #pragma unroll
            for (int ss = 4; ss < 20; ++ss) {
                int sgh = ws * 16 + (ss - 4);
                a[ss].s = *(const short8*)(hnext
                    + (size_t)(((mt * 32 + sgh) * 4 + q4) * 16 + em) * 8);
            }
        }
    }
}

// ---------------------------------------------------------------------------
// FC + log_softmax: one wave per batch row. logits[b][c] = h.fc_w[c] + fc_b[c]
// ---------------------------------------------------------------------------
extern "C" __global__ void fc_logsoftmax(const float* __restrict__ hlast,
                                         const float* __restrict__ fcw,
                                         const float* __restrict__ fcb,
                                         float* __restrict__ out)
{
    int b = blockIdx.x, c = threadIdx.x;  // 64 threads, 1 wave
    float acc = 0.0f;
    if (c < C_DIM) {
        const float* wr = fcw + (size_t)c * H_DIM;
        const float* hr = hlast + (size_t)b * H_DIM;
        for (int k = 0; k < H_DIM; k += 4) {
            float4 hv = *(const float4*)(hr + k);
            float4 wv = *(const float4*)(wr + k);
            acc += hv.x * wv.x + hv.y * wv.y + hv.z * wv.z + hv.w * wv.w;
        }
        acc += fcb[c];
    }
    float logit = (c < C_DIM) ? acc : -1e30f;
    float mx = logit;
    #pragma unroll
    for (int off = 32; off; off >>= 1) mx = fmaxf(mx, __shfl_xor(mx, off));
    float e = (c < C_DIM) ? expf(logit - mx) : 0.0f;
    float sum = e;
    #pragma unroll
    for (int off = 32; off; off >>= 1) sum += __shfl_xor(sum, off);
    if (c < C_DIM) out[b * C_DIM + c] = logit - mx - logf(sum);
}

extern "C" void kernel_launch(void* const* d_in, const int* in_sizes, int n_in,
                              void* d_out, int out_size, void* d_ws, size_t ws_size,
                              hipStream_t stream)
{
    const float* inputs = (const float*)d_in[0];
    const float* Wih    = (const float*)d_in[1];
    const float* Whh    = (const float*)d_in[2];
    const float* bih    = (const float*)d_in[3];
    const float* bhh    = (const float*)d_in[4];
    const float* fcw    = (const float*)d_in[5];
    const float* fcb    = (const float*)d_in[6];
    float* out = (float*)d_out;

    char* ws = (char*)d_ws;
    u16*   xswz  = (u16*)(ws + WS_XSWZ);
    u16*   hswz  = (u16*)(ws + WS_HSWZ);
    float* hlast = (float*)(ws + WS_HLAST);

    // slot 0 = h_0 = 0 (t=0 skips tag check). Slots t>=1 keep harness poison
    // 0xAA whose tag lsb is 0 -> never validates before the producer's store.
    hipMemsetAsync(hswz, 0, B_DIM * H_DIM * sizeof(u16), stream);

    prep_x<<<2048, 256, 0, stream>>>(inputs, xswz);

    (void)hipFuncSetAttribute((const void*)lstm_scan,
                              hipFuncAttributeMaxDynamicSharedMemorySize, LDS_TOTAL);
    lstm_scan<<<NWG, 1024, LDS_TOTAL, stream>>>(xswz, hswz, Wih, Whh, bih, bhh, hlast);
    fc_logsoftmax<<<B_DIM, 64, 0, stream>>>(hlast, fcw, fcb, out);
}

// Round 10
// 1222.937 us; speedup vs baseline: 2.1384x; 2.1384x over previous
//
#include <hip/hip_runtime.h>
#include <hip/hip_bf16.h>

typedef unsigned short u16;
typedef unsigned int u32;
typedef unsigned long long u64;
typedef __attribute__((ext_vector_type(8))) short short8;
typedef __attribute__((ext_vector_type(4))) float floatx4;

#define I_DIM 256
#define H_DIM 1024
#define B_DIM 64
#define T_DIM 256
#define C_DIM 60
#define NWG   128
#define UPW   8      // hidden units per WG
#define BSTR  20     // pacc row stride (dwords): 16B-aligned, conflict-free pointwise

// LDS layout (bytes)
#define LDS_W_OFF    0        // 2*40*4*16 frags * 16B = 81920
#define LDS_BIAS_OFF 81920    // 32*4 = 128
#define LDS_PACC_OFF 82048    // 4 streams * 2 bufs * 64 rows * 20 dw * 4B = 40960
#define LDS_FLAG_OFF 123008   // 4 ints
#define LDS_TOTAL    123040

// workspace layout (bytes)
#define WS_XSWZ   0u          // T*B*I bf16 = 8388608
#define WS_HSWZ   8388608u    // 256 slots * 64*1024 bf16 = 33554432 (never reused)
#define WS_HLAST  41943040u   // 64*1024 f32 = 262144

#define LSBM 0x0001000100010001ull

__device__ __forceinline__ u16 f2bf(float f) {
    u32 u = __float_as_uint(f);
    u32 r = (u + 0x7fffu + ((u >> 16) & 1u)) >> 16;
    return (u16)r;
}
__device__ __forceinline__ float fsig(float x) { return 1.0f / (1.0f + __expf(-x)); }
__device__ __forceinline__ float ftanh(float x) { return 2.0f * fsig(2.0f * x) - 1.0f; }

union hfrag { short8 s; u64 q[2]; };

// ---------------------------------------------------------------------------
// Pre-swizzle inputs [B][T][I] fp32 -> xswz[t] bf16 in MFMA-A-fragment layout:
// 16B unit index (per t): ((mt*8 + s)*4 + q)*16 + m  holds A[b=mt*16+m][k=s*32+q*8 .. +7]
// ---------------------------------------------------------------------------
extern "C" __global__ void prep_x(const float* __restrict__ in, u16* __restrict__ xswz) {
    int o = blockIdx.x * 256 + threadIdx.x;           // octet index, 524288 total
    int m = o & 15, q = (o >> 4) & 3, s = (o >> 6) & 7, mt = (o >> 9) & 3, t = o >> 11;
    int b = mt * 16 + m, k = s * 32 + q * 8;
    const float* src = in + ((size_t)(b * T_DIM + t)) * I_DIM + k;
    float4 v0 = *(const float4*)src;
    float4 v1 = *(const float4*)(src + 4);
    short8 val;
    val[0] = (short)f2bf(v0.x); val[1] = (short)f2bf(v0.y);
    val[2] = (short)f2bf(v0.z); val[3] = (short)f2bf(v0.w);
    val[4] = (short)f2bf(v1.x); val[5] = (short)f2bf(v1.y);
    val[6] = (short)f2bf(v1.z); val[7] = (short)f2bf(v1.w);
    *(short8*)(xswz + (size_t)o * 8) = val;
}

// ---------------------------------------------------------------------------
// Persistent LSTM scan (r19): r16 VERBATIM (the proven 865us structure:
// 4 independent 2-wave streams, 2 waves/SIMD, one LDS rendezvous, dbuf pacc,
// tagged ack-free publish, throttled agent repair) with two TIMING-ONLY
// changes motivated by step arithmetic (865/256 = 3.38us/step, of which the
// fixed PACE=5 sleep was 1.07us serial AND phase-locked across streams so
// all 4 streams slept together):
//  (1) ADAPTIVE PACE: start 3, floor 2 (~0.43us ~ true store visibility),
//      +4 on any repair round (cap 16), -1 per clean step. Safe to anneal
//      now: a sleeping/spinning stream's SIMD slots are used by its
//      co-resident stream.
//  (2) PHASE STAGGER: streams 2,3 (SIMD-mates of 0,1) take a one-time
//      ~0.6us sleep before the loop. Streams are INDEPENDENT global
//      networks (stream s of WG j depends only on stream s of other WGs --
//      batch groups never mix), so the offset persists and co-resident
//      streams fill each other's sleeps instead of sleeping in unison.
// r17/r18 lesson applied: do NOT restructure the stream unit.
// ---------------------------------------------------------------------------
extern "C" __global__ void __launch_bounds__(512, 2) lstm_scan(
    const u16* __restrict__ xswz, u16* hswz,
    const float* __restrict__ Wih, const float* __restrict__ Whh,
    const float* __restrict__ bih, const float* __restrict__ bhh,
    float* hlast)
{
    extern __shared__ char lds[];
    u16*   Wlds = (u16*)(lds + LDS_W_OFF);
    float* bias = (float*)(lds + LDS_BIAS_OFF);
    float* pacc = (float*)(lds + LDS_PACC_OFF);
    int*   sbf  = (int*)(lds + LDS_FLAG_OFF);

    const int j    = blockIdx.x;
    const int tid  = threadIdx.x;
    const int lane = tid & 63;
    const int w    = tid >> 6;
    const int s    = w >> 1;      // stream = pipeline 0..3
    const int ws   = w & 1;       // wave within stream

    // ---- stage W slice into LDS, bf16, B-swizzled:
    // unit wu = ((nt*40 + sg)*4 + q)*16 + nn  holds W[r(nt,nn)][sg*32+q*8 .. +7]
    for (int i = 0; i < 10; ++i) {
        int wu = tid + i * 512;
        int nn = wu & 15, q = (wu >> 4) & 3, rest = wu >> 6;
        int sg = rest % 40, nt = rest / 40;
        int n = nt * 16 + nn;
        int g = n >> 3, uu = n & 7;
        int r = g * H_DIM + j * UPW + uu;
        int kb = sg * 32 + q * 8;
        const float* src = (kb < I_DIM) ? (Wih + (size_t)r * I_DIM + kb)
                                        : (Whh + (size_t)r * H_DIM + (kb - I_DIM));
        short8 val;
        #pragma unroll
        for (int e = 0; e < 8; ++e) val[e] = (short)f2bf(src[e]);
        *(short8*)(Wlds + (size_t)wu * 8) = val;
    }
    if (tid < 32) {
        int n = tid, g = n >> 3, uu = n & 7;
        int r = g * H_DIM + j * UPW + uu;
        bias[n] = bih[r] + bhh[r];
    }
    if (tid < 4) sbf[tid] = 0;
    __syncthreads();   // last WG-wide barrier in the kernel

    const int m16 = lane & 15, q4 = lane >> 4;
    const int sl    = ws * 64 + lane;   // 0..127 within stream
    const int pw_pm = sl >> 3;          // batch-in-16
    const int pw_uu = sl & 7;           // hidden unit within WG's 8
    float creg = 0.0f;                  // c state for this lane's item
    float* pacc_s = pacc + s * (2 * 64 * BSTR);
    int*   flag   = sbf + s;

    // A-frags: ss 0..3 = x (sg = ws*4+ss), ss 4..19 = h (sgh = ws*16+ss-4)
    hfrag a[20];

    // ---- prologue: loads for t=0 (slot 0 = h_0 = 0, no tag check at t=0)
    #pragma unroll
    for (int ss = 0; ss < 4; ++ss) {
        int sg = ws * 4 + ss;
        a[ss].s = *(const short8*)(xswz
            + (size_t)(((s * 8 + sg) * 4 + q4) * 16 + m16) * 8);
    }
    #pragma unroll
    for (int ss = 4; ss < 20; ++ss) {
        int sgh = ws * 16 + (ss - 4);
        a[ss].s = *(const short8*)(hswz
            + (size_t)(((s * 32 + sgh) * 4 + q4) * 16 + m16) * 8);
    }

    // ---- phase stagger: SIMD-mate streams (2,3) offset by ~0.6us so
    // co-resident streams alternate sleep/compute instead of phase-locking
    for (int p = 0; p < (s >> 1) * 3; ++p) __builtin_amdgcn_s_sleep(8);

    int pace = 3;   // adaptive visibility sleep, units of s_sleep(8) (~0.21us)

    for (int t = 0; t < T_DIM; ++t) {
        const u16* hbase = hswz + (size_t)t * (B_DIM * H_DIM);   // fresh slot
        u16*       hnext = hswz + (size_t)(t + 1) * (B_DIM * H_DIM);
        const u16* xnext = xswz + (size_t)(t + 1) * (B_DIM * I_DIM);
        const int  En    = (t % 13) + 1;          // tag nibble, never 0
        const u64  Eq    = (u64)(En & 1) | ((u64)((En >> 1) & 1) << 16)
                         | ((u64)((En >> 2) & 1) << 32) | ((u64)((En >> 3) & 1) << 48);
        const int  Ep    = ((t + 1) % 13) + 1;

        // ---- x part: 8 MFMAs while h loads (still in flight) arrive
        floatx4 acc[2];
        acc[0] = (floatx4){0.f, 0.f, 0.f, 0.f};
        acc[1] = (floatx4){0.f, 0.f, 0.f, 0.f};
        #pragma unroll
        for (int ss = 0; ss < 4; ++ss) {
            int sg = ws * 4 + ss;
            #pragma unroll
            for (int nt = 0; nt < 2; ++nt) {
                short8 bv = *(const short8*)(Wlds
                    + (size_t)(((nt * 40 + sg) * 4 + q4) * 16 + m16) * 8);
                acc[nt] = __builtin_amdgcn_mfma_f32_16x16x32_bf16(
                    a[ss].s, bv, acc[nt], 0, 0, 0);
            }
        }

        // ---- validate h-frag tags; throttled agent-scope repair
        int rounds = 0;
        if (t > 0) {
            u32 mk = 0;
            #pragma unroll
            for (int ss = 4; ss < 20; ++ss)
                if ((((a[ss].q[0] ^ Eq) | (a[ss].q[1] ^ Eq)) & LSBM) != 0)
                    mk |= 1u << ss;
            while (__any(mk != 0)) {
                ++rounds;
                #pragma unroll
                for (int ss = 4; ss < 20; ++ss)
                    if ((mk >> ss) & 1) {
                        int sgh = ws * 16 + (ss - 4);
                        const u64* pp = (const u64*)hbase
                            + (size_t)(((s * 32 + sgh) * 4 + q4) * 16 + m16) * 2;
                        a[ss].q[0] = __hip_atomic_load(pp,     __ATOMIC_RELAXED, __HIP_MEMORY_SCOPE_AGENT);
                        a[ss].q[1] = __hip_atomic_load(pp + 1, __ATOMIC_RELAXED, __HIP_MEMORY_SCOPE_AGENT);
                    }
                #pragma unroll
                for (int ss = 4; ss < 20; ++ss)
                    if (((mk >> ss) & 1) &&
                        ((((a[ss].q[0] ^ Eq) | (a[ss].q[1] ^ Eq)) & LSBM) == 0))
                        mk &= ~(1u << ss);
                if (__any(mk != 0)) {
                    if (rounds < 4) __builtin_amdgcn_s_sleep(4);
                    else            __builtin_amdgcn_s_sleep(16);
                }
            }
            // pace feedback: repair means we fetched too early
            if (rounds > 0) { pace += 4; if (pace > 16) pace = 16; }
            else if (pace > 2) --pace;
        }

        // ---- h part: 32 MFMAs (16 h-sg x 2 ntiles)
        #pragma unroll
        for (int ss = 4; ss < 20; ++ss) {
            int sg = 8 + ws * 16 + (ss - 4);
            #pragma unroll
            for (int nt = 0; nt < 2; ++nt) {
                short8 bv = *(const short8*)(Wlds
                    + (size_t)(((nt * 40 + sg) * 4 + q4) * 16 + m16) * 8);
                acc[nt] = __builtin_amdgcn_mfma_f32_16x16x32_bf16(
                    a[ss].s, bv, acc[nt], 0, 0, 0);
            }
        }

        // ---- K-partials to stream-private pacc[t&1] (transposed)
        float* pc = pacc_s + (t & 1) * (64 * BSTR);
        #pragma unroll
        for (int nt = 0; nt < 2; ++nt)
            *(floatx4*)(pc + (ws * 32 + nt * 16 + m16) * BSTR + q4 * 4) = acc[nt];

        // ---- stream sub-barrier (monotonic LDS counter, 2 waves)
        asm volatile("s_waitcnt lgkmcnt(0)" ::: "memory");
        if (lane == 0)
            __hip_atomic_fetch_add(flag, 1, __ATOMIC_RELAXED,
                                   __HIP_MEMORY_SCOPE_WORKGROUP);
        {
            const int tgt = 2 * (t + 1);
            while (__hip_atomic_load(flag, __ATOMIC_RELAXED,
                                     __HIP_MEMORY_SCOPE_WORKGROUP) < tgt)
                __builtin_amdgcn_s_sleep(1);
        }
        asm volatile("" ::: "memory");

        // ---- pointwise: reduce 2 wave-partials, gates, c/h; tagged publish
        {
            float sv[4];
            #pragma unroll
            for (int g = 0; g < 4; ++g) {
                sv[g] = bias[g * 8 + pw_uu]
                      + pc[(g * 8 + pw_uu) * BSTR + pw_pm]
                      + pc[(32 + g * 8 + pw_uu) * BSTR + pw_pm];
            }
            float ig = fsig(sv[0]), fg = fsig(sv[1]), gg = ftanh(sv[2]), og = fsig(sv[3]);
            float c = fg * creg + ig * gg;
            creg = c;
            float h = og * ftanh(c);
            if (t == T_DIM - 1) {
                hlast[(size_t)(s * 16 + pw_pm) * H_DIM + j * UPW + pw_uu] = h;
            } else {
                u16 hb16 = (u16)((f2bf(h) & 0xFFFEu) | ((u32)(Ep >> (pw_uu & 3)) & 1u));
                // unit octet ((s*32 + (j>>2))*4 + (j&3))*16 + pm, elem uu
                u16* dst = hnext
                    + (size_t)((s * 32 + (j >> 2)) * 4 + (j & 3)) * 128 + sl;
                __hip_atomic_store(dst, hb16, __ATOMIC_RELAXED,
                                   __HIP_MEMORY_SCOPE_AGENT);
            }
        }
        asm volatile("" ::: "memory");

        // ---- issue next step's loads: x now (tag-free), h after the
        // visibility sleep (sleep covered by the co-resident stream)
        if (t + 1 < T_DIM) {
            #pragma unroll
            for (int ss = 0; ss < 4; ++ss) {
                int sg = ws * 4 + ss;
                a[ss].s = *(const short8*)(xnext
                    + (size_t)(((s * 8 + sg) * 4 + q4) * 16 + m16) * 8);
            }
            for (int p = 0; p < pace; ++p) __builtin_amdgcn_s_sleep(8);
            #pragma unroll
            for (int ss = 4; ss < 20; ++ss) {
                int sgh = ws * 16 + (ss - 4);
                a[ss].s = *(const short8*)(hnext
                    + (size_t)(((s * 32 + sgh) * 4 + q4) * 16 + m16) * 8);
            }
        }
    }
}

// ---------------------------------------------------------------------------
// FC + log_softmax: one wave per batch row. logits[b][c] = h.fc_w[c] + fc_b[c]
// ---------------------------------------------------------------------------
extern "C" __global__ void fc_logsoftmax(const float* __restrict__ hlast,
                                         const float* __restrict__ fcw,
                                         const float* __restrict__ fcb,
                                         float* __restrict__ out)
{
    int b = blockIdx.x, c = threadIdx.x;  // 64 threads, 1 wave
    float acc = 0.0f;
    if (c < C_DIM) {
        const float* wr = fcw + (size_t)c * H_DIM;
        const float* hr = hlast + (size_t)b * H_DIM;
        for (int k = 0; k < H_DIM; k += 4) {
            float4 hv = *(const float4*)(hr + k);
            float4 wv = *(const float4*)(wr + k);
            acc += hv.x * wv.x + hv.y * wv.y + hv.z * wv.z + hv.w * wv.w;
        }
        acc += fcb[c];
    }
    float logit = (c < C_DIM) ? acc : -1e30f;
    float mx = logit;
    #pragma unroll
    for (int off = 32; off; off >>= 1) mx = fmaxf(mx, __shfl_xor(mx, off));
    float e = (c < C_DIM) ? expf(logit - mx) : 0.0f;
    float sum = e;
    #pragma unroll
    for (int off = 32; off; off >>= 1) sum += __shfl_xor(sum, off);
    if (c < C_DIM) out[b * C_DIM + c] = logit - mx - logf(sum);
}

extern "C" void kernel_launch(void* const* d_in, const int* in_sizes, int n_in,
                              void* d_out, int out_size, void* d_ws, size_t ws_size,
                              hipStream_t stream)
{
    const float* inputs = (const float*)d_in[0];
    const float* Wih    = (const float*)d_in[1];
    const float* Whh    = (const float*)d_in[2];
    const float* bih    = (const float*)d_in[3];
    const float* bhh    = (const float*)d_in[4];
    const float* fcw    = (const float*)d_in[5];
    const float* fcb    = (const float*)d_in[6];
    float* out = (float*)d_out;

    char* ws = (char*)d_ws;
    u16*   xswz  = (u16*)(ws + WS_XSWZ);
    u16*   hswz  = (u16*)(ws + WS_HSWZ);
    float* hlast = (float*)(ws + WS_HLAST);

    // slot 0 = h_0 = 0 (t=0 skips tag check). Slots t>=1 keep harness poison
    // 0xAA whose tag lsb is 0 -> never validates before the producer's store.
    hipMemsetAsync(hswz, 0, B_DIM * H_DIM * sizeof(u16), stream);

    prep_x<<<2048, 256, 0, stream>>>(inputs, xswz);

    (void)hipFuncSetAttribute((const void*)lstm_scan,
                              hipFuncAttributeMaxDynamicSharedMemorySize, LDS_TOTAL);
    lstm_scan<<<NWG, 512, LDS_TOTAL, stream>>>(xswz, hswz, Wih, Whh, bih, bhh, hlast);
    fc_logsoftmax<<<B_DIM, 64, 0, stream>>>(hlast, fcw, fcb, out);
}

// Round 11
// 931.292 us; speedup vs baseline: 2.8080x; 1.3132x over previous
//
#include <hip/hip_runtime.h>
#include <hip/hip_bf16.h>

typedef unsigned short u16;
typedef unsigned int u32;
typedef unsigned long long u64;
typedef __attribute__((ext_vector_type(8))) short short8;
typedef __attribute__((ext_vector_type(4))) float floatx4;

#define I_DIM 256
#define H_DIM 1024
#define B_DIM 64
#define T_DIM 256
#define C_DIM 60
#define NWG   128
#define UPW   8      // hidden units per WG
#define BSTR  20     // pacc row stride (dwords): 16B-aligned, conflict-free pointwise
#define PACE  5      // post-publish visibility sleep, units of s_sleep(8) (FIXED:
                     // r19 proved adaptive annealing trades cheap sleep for
                     // expensive repair rounds -- do not anneal)
#define STAG  8      // one-time phase stagger for SIMD-mate streams (~1.7us,
                     // about half the 3.38us step period -> anti-phase sleeps)

// LDS layout (bytes)
#define LDS_W_OFF    0        // 2*40*4*16 frags * 16B = 81920
#define LDS_BIAS_OFF 81920    // 32*4 = 128
#define LDS_PACC_OFF 82048    // 4 streams * 2 bufs * 64 rows * 20 dw * 4B = 40960
#define LDS_FLAG_OFF 123008   // 4 ints
#define LDS_TOTAL    123040

// workspace layout (bytes)
#define WS_XSWZ   0u          // T*B*I bf16 = 8388608
#define WS_HSWZ   8388608u    // 256 slots * 64*1024 bf16 = 33554432 (never reused)
#define WS_HLAST  41943040u   // 64*1024 f32 = 262144

#define LSBM 0x0001000100010001ull

__device__ __forceinline__ u16 f2bf(float f) {
    u32 u = __float_as_uint(f);
    u32 r = (u + 0x7fffu + ((u >> 16) & 1u)) >> 16;
    return (u16)r;
}
__device__ __forceinline__ float fsig(float x) { return 1.0f / (1.0f + __expf(-x)); }
__device__ __forceinline__ float ftanh(float x) { return 2.0f * fsig(2.0f * x) - 1.0f; }

union hfrag { short8 s; u64 q[2]; };

// ---------------------------------------------------------------------------
// Pre-swizzle inputs [B][T][I] fp32 -> xswz[t] bf16 in MFMA-A-fragment layout:
// 16B unit index (per t): ((mt*8 + s)*4 + q)*16 + m  holds A[b=mt*16+m][k=s*32+q*8 .. +7]
// ---------------------------------------------------------------------------
extern "C" __global__ void prep_x(const float* __restrict__ in, u16* __restrict__ xswz) {
    int o = blockIdx.x * 256 + threadIdx.x;           // octet index, 524288 total
    int m = o & 15, q = (o >> 4) & 3, s = (o >> 6) & 7, mt = (o >> 9) & 3, t = o >> 11;
    int b = mt * 16 + m, k = s * 32 + q * 8;
    const float* src = in + ((size_t)(b * T_DIM + t)) * I_DIM + k;
    float4 v0 = *(const float4*)src;
    float4 v1 = *(const float4*)(src + 4);
    short8 val;
    val[0] = (short)f2bf(v0.x); val[1] = (short)f2bf(v0.y);
    val[2] = (short)f2bf(v0.z); val[3] = (short)f2bf(v0.w);
    val[4] = (short)f2bf(v1.x); val[5] = (short)f2bf(v1.y);
    val[6] = (short)f2bf(v1.z); val[7] = (short)f2bf(v1.w);
    *(short8*)(xswz + (size_t)o * 8) = val;
}

// ---------------------------------------------------------------------------
// Persistent LSTM scan (r20): r16 VERBATIM (the proven 865us operating
// point: 4 independent 2-wave streams, 2 waves/SIMD, one LDS-atomic
// rendezvous per step, dbuf pacc, ack-free tagged 2B publish with
// tag=(t%13)+1 per-u16 lsb (never 0=poison), throttled agent repair,
// FIXED PACE=5 visibility sleep, slot-per-step hswz) + exactly ONE change:
//   HALF-PERIOD PHASE STAGGER. r16's 1.07us/step sleep is phase-locked
//   across the CU's 4 streams (all sleep in unison -> SIMD idles). Streams
//   are independent global networks (stream s of WG j depends only on
//   stream s of other WGs) with identical natural periods, so a one-time
//   ~1.7us offset (half the 3.38us step period) for streams 2,3 -- the
//   SIMD-mates of 0,1 -- persists and anti-phases the sleeps: while 0,1
//   sleep, 2,3 compute on the same SIMDs, and vice versa.
// r19 lesson baked in: PACE stays FIXED (adaptive annealing equilibrates at
// the repair boundary and converts cheap sleep into expensive repair).
// ---------------------------------------------------------------------------
extern "C" __global__ void __launch_bounds__(512, 2) lstm_scan(
    const u16* __restrict__ xswz, u16* hswz,
    const float* __restrict__ Wih, const float* __restrict__ Whh,
    const float* __restrict__ bih, const float* __restrict__ bhh,
    float* hlast)
{
    extern __shared__ char lds[];
    u16*   Wlds = (u16*)(lds + LDS_W_OFF);
    float* bias = (float*)(lds + LDS_BIAS_OFF);
    float* pacc = (float*)(lds + LDS_PACC_OFF);
    int*   sbf  = (int*)(lds + LDS_FLAG_OFF);

    const int j    = blockIdx.x;
    const int tid  = threadIdx.x;
    const int lane = tid & 63;
    const int w    = tid >> 6;
    const int s    = w >> 1;      // stream = pipeline 0..3
    const int ws   = w & 1;       // wave within stream

    // ---- stage W slice into LDS, bf16, B-swizzled:
    // unit wu = ((nt*40 + sg)*4 + q)*16 + nn  holds W[r(nt,nn)][sg*32+q*8 .. +7]
    for (int i = 0; i < 10; ++i) {
        int wu = tid + i * 512;
        int nn = wu & 15, q = (wu >> 4) & 3, rest = wu >> 6;
        int sg = rest % 40, nt = rest / 40;
        int n = nt * 16 + nn;
        int g = n >> 3, uu = n & 7;
        int r = g * H_DIM + j * UPW + uu;
        int kb = sg * 32 + q * 8;
        const float* src = (kb < I_DIM) ? (Wih + (size_t)r * I_DIM + kb)
                                        : (Whh + (size_t)r * H_DIM + (kb - I_DIM));
        short8 val;
        #pragma unroll
        for (int e = 0; e < 8; ++e) val[e] = (short)f2bf(src[e]);
        *(short8*)(Wlds + (size_t)wu * 8) = val;
    }
    if (tid < 32) {
        int n = tid, g = n >> 3, uu = n & 7;
        int r = g * H_DIM + j * UPW + uu;
        bias[n] = bih[r] + bhh[r];
    }
    if (tid < 4) sbf[tid] = 0;
    __syncthreads();   // last WG-wide barrier in the kernel

    const int m16 = lane & 15, q4 = lane >> 4;
    const int sl    = ws * 64 + lane;   // 0..127 within stream
    const int pw_pm = sl >> 3;          // batch-in-16
    const int pw_uu = sl & 7;           // hidden unit within WG's 8
    float creg = 0.0f;                  // c state for this lane's item
    float* pacc_s = pacc + s * (2 * 64 * BSTR);
    int*   flag   = sbf + s;

    // A-frags: ss 0..3 = x (sg = ws*4+ss), ss 4..19 = h (sgh = ws*16+ss-4)
    hfrag a[20];

    // ---- prologue: loads for t=0 (slot 0 = h_0 = 0, no tag check at t=0)
    #pragma unroll
    for (int ss = 0; ss < 4; ++ss) {
        int sg = ws * 4 + ss;
        a[ss].s = *(const short8*)(xswz
            + (size_t)(((s * 8 + sg) * 4 + q4) * 16 + m16) * 8);
    }
    #pragma unroll
    for (int ss = 4; ss < 20; ++ss) {
        int sgh = ws * 16 + (ss - 4);
        a[ss].s = *(const short8*)(hswz
            + (size_t)(((s * 32 + sgh) * 4 + q4) * 16 + m16) * 8);
    }

    // ---- ONE-TIME half-period stagger: streams 2,3 (SIMD-mates of 0,1)
    // offset ~1.7us so co-resident streams' sleeps anti-phase
    for (int p = 0; p < (s >> 1) * STAG; ++p) __builtin_amdgcn_s_sleep(8);

    for (int t = 0; t < T_DIM; ++t) {
        const u16* hbase = hswz + (size_t)t * (B_DIM * H_DIM);   // fresh slot
        u16*       hnext = hswz + (size_t)(t + 1) * (B_DIM * H_DIM);
        const u16* xnext = xswz + (size_t)(t + 1) * (B_DIM * I_DIM);
        const int  En    = (t % 13) + 1;          // tag nibble, never 0
        const u64  Eq    = (u64)(En & 1) | ((u64)((En >> 1) & 1) << 16)
                         | ((u64)((En >> 2) & 1) << 32) | ((u64)((En >> 3) & 1) << 48);
        const int  Ep    = ((t + 1) % 13) + 1;

        // ---- x part: 8 MFMAs while h loads (still in flight) arrive
        floatx4 acc[2];
        acc[0] = (floatx4){0.f, 0.f, 0.f, 0.f};
        acc[1] = (floatx4){0.f, 0.f, 0.f, 0.f};
        #pragma unroll
        for (int ss = 0; ss < 4; ++ss) {
            int sg = ws * 4 + ss;
            #pragma unroll
            for (int nt = 0; nt < 2; ++nt) {
                short8 bv = *(const short8*)(Wlds
                    + (size_t)(((nt * 40 + sg) * 4 + q4) * 16 + m16) * 8);
                acc[nt] = __builtin_amdgcn_mfma_f32_16x16x32_bf16(
                    a[ss].s, bv, acc[nt], 0, 0, 0);
            }
        }

        // ---- validate h-frag tags; throttled agent-scope repair
        if (t > 0) {
            u32 mk = 0;
            #pragma unroll
            for (int ss = 4; ss < 20; ++ss)
                if ((((a[ss].q[0] ^ Eq) | (a[ss].q[1] ^ Eq)) & LSBM) != 0)
                    mk |= 1u << ss;
            int rounds = 0;
            while (__any(mk != 0)) {
                ++rounds;
                #pragma unroll
                for (int ss = 4; ss < 20; ++ss)
                    if ((mk >> ss) & 1) {
                        int sgh = ws * 16 + (ss - 4);
                        const u64* pp = (const u64*)hbase
                            + (size_t)(((s * 32 + sgh) * 4 + q4) * 16 + m16) * 2;
                        a[ss].q[0] = __hip_atomic_load(pp,     __ATOMIC_RELAXED, __HIP_MEMORY_SCOPE_AGENT);
                        a[ss].q[1] = __hip_atomic_load(pp + 1, __ATOMIC_RELAXED, __HIP_MEMORY_SCOPE_AGENT);
                    }
                #pragma unroll
                for (int ss = 4; ss < 20; ++ss)
                    if (((mk >> ss) & 1) &&
                        ((((a[ss].q[0] ^ Eq) | (a[ss].q[1] ^ Eq)) & LSBM) == 0))
                        mk &= ~(1u << ss);
                if (__any(mk != 0)) {
                    if (rounds < 4) __builtin_amdgcn_s_sleep(4);
                    else            __builtin_amdgcn_s_sleep(16);
                }
            }
        }

        // ---- h part: 32 MFMAs (16 h-sg x 2 ntiles)
        #pragma unroll
        for (int ss = 4; ss < 20; ++ss) {
            int sg = 8 + ws * 16 + (ss - 4);
            #pragma unroll
            for (int nt = 0; nt < 2; ++nt) {
                short8 bv = *(const short8*)(Wlds
                    + (size_t)(((nt * 40 + sg) * 4 + q4) * 16 + m16) * 8);
                acc[nt] = __builtin_amdgcn_mfma_f32_16x16x32_bf16(
                    a[ss].s, bv, acc[nt], 0, 0, 0);
            }
        }

        // ---- K-partials to stream-private pacc[t&1] (transposed)
        float* pc = pacc_s + (t & 1) * (64 * BSTR);
        #pragma unroll
        for (int nt = 0; nt < 2; ++nt)
            *(floatx4*)(pc + (ws * 32 + nt * 16 + m16) * BSTR + q4 * 4) = acc[nt];

        // ---- stream sub-barrier (monotonic LDS counter, 2 waves)
        asm volatile("s_waitcnt lgkmcnt(0)" ::: "memory");
        if (lane == 0)
            __hip_atomic_fetch_add(flag, 1, __ATOMIC_RELAXED,
                                   __HIP_MEMORY_SCOPE_WORKGROUP);
        {
            const int tgt = 2 * (t + 1);
            while (__hip_atomic_load(flag, __ATOMIC_RELAXED,
                                     __HIP_MEMORY_SCOPE_WORKGROUP) < tgt)
                __builtin_amdgcn_s_sleep(1);
        }
        asm volatile("" ::: "memory");

        // ---- pointwise: reduce 2 wave-partials, gates, c/h; tagged publish
        {
            float sv[4];
            #pragma unroll
            for (int g = 0; g < 4; ++g) {
                sv[g] = bias[g * 8 + pw_uu]
                      + pc[(g * 8 + pw_uu) * BSTR + pw_pm]
                      + pc[(32 + g * 8 + pw_uu) * BSTR + pw_pm];
            }
            float ig = fsig(sv[0]), fg = fsig(sv[1]), gg = ftanh(sv[2]), og = fsig(sv[3]);
            float c = fg * creg + ig * gg;
            creg = c;
            float h = og * ftanh(c);
            if (t == T_DIM - 1) {
                hlast[(size_t)(s * 16 + pw_pm) * H_DIM + j * UPW + pw_uu] = h;
            } else {
                u16 hb16 = (u16)((f2bf(h) & 0xFFFEu) | ((u32)(Ep >> (pw_uu & 3)) & 1u));
                // unit octet ((s*32 + (j>>2))*4 + (j&3))*16 + pm, elem uu
                u16* dst = hnext
                    + (size_t)((s * 32 + (j >> 2)) * 4 + (j & 3)) * 128 + sl;
                __hip_atomic_store(dst, hb16, __ATOMIC_RELAXED,
                                   __HIP_MEMORY_SCOPE_AGENT);
            }
        }
        asm volatile("" ::: "memory");

        // ---- issue next step's loads: x now (tag-free), h after the
        // visibility sleep (sleep covered by the anti-phased co-stream)
        if (t + 1 < T_DIM) {
            #pragma unroll
            for (int ss = 0; ss < 4; ++ss) {
                int sg = ws * 4 + ss;
                a[ss].s = *(const short8*)(xnext
                    + (size_t)(((s * 8 + sg) * 4 + q4) * 16 + m16) * 8);
            }
            for (int p = 0; p < PACE; ++p) __builtin_amdgcn_s_sleep(8);
            #pragma unroll
            for (int ss = 4; ss < 20; ++ss) {
                int sgh = ws * 16 + (ss - 4);
                a[ss].s = *(const short8*)(hnext
                    + (size_t)(((s * 32 + sgh) * 4 + q4) * 16 + m16) * 8);
            }
        }
    }
}

// ---------------------------------------------------------------------------
// FC + log_softmax: one wave per batch row. logits[b][c] = h.fc_w[c] + fc_b[c]
// ---------------------------------------------------------------------------
extern "C" __global__ void fc_logsoftmax(const float* __restrict__ hlast,
                                         const float* __restrict__ fcw,
                                         const float* __restrict__ fcb,
                                         float* __restrict__ out)
{
    int b = blockIdx.x, c = threadIdx.x;  // 64 threads, 1 wave
    float acc = 0.0f;
    if (c < C_DIM) {
        const float* wr = fcw + (size_t)c * H_DIM;
        const float* hr = hlast + (size_t)b * H_DIM;
        for (int k = 0; k < H_DIM; k += 4) {
            float4 hv = *(const float4*)(hr + k);
            float4 wv = *(const float4*)(wr + k);
            acc += hv.x * wv.x + hv.y * wv.y + hv.z * wv.z + hv.w * wv.w;
        }
        acc += fcb[c];
    }
    float logit = (c < C_DIM) ? acc : -1e30f;
    float mx = logit;
    #pragma unroll
    for (int off = 32; off; off >>= 1) mx = fmaxf(mx, __shfl_xor(mx, off));
    float e = (c < C_DIM) ? expf(logit - mx) : 0.0f;
    float sum = e;
    #pragma unroll
    for (int off = 32; off; off >>= 1) sum += __shfl_xor(sum, off);
    if (c < C_DIM) out[b * C_DIM + c] = logit - mx - logf(sum);
}

extern "C" void kernel_launch(void* const* d_in, const int* in_sizes, int n_in,
                              void* d_out, int out_size, void* d_ws, size_t ws_size,
                              hipStream_t stream)
{
    const float* inputs = (const float*)d_in[0];
    const float* Wih    = (const float*)d_in[1];
    const float* Whh    = (const float*)d_in[2];
    const float* bih    = (const float*)d_in[3];
    const float* bhh    = (const float*)d_in[4];
    const float* fcw    = (const float*)d_in[5];
    const float* fcb    = (const float*)d_in[6];
    float* out = (float*)d_out;

    char* ws = (char*)d_ws;
    u16*   xswz  = (u16*)(ws + WS_XSWZ);
    u16*   hswz  = (u16*)(ws + WS_HSWZ);
    float* hlast = (float*)(ws + WS_HLAST);

    // slot 0 = h_0 = 0 (t=0 skips tag check). Slots t>=1 keep harness poison
    // 0xAA whose tag lsb is 0 -> never validates before the producer's store.
    hipMemsetAsync(hswz, 0, B_DIM * H_DIM * sizeof(u16), stream);

    prep_x<<<2048, 256, 0, stream>>>(inputs, xswz);

    (void)hipFuncSetAttribute((const void*)lstm_scan,
                              hipFuncAttributeMaxDynamicSharedMemorySize, LDS_TOTAL);
    lstm_scan<<<NWG, 512, LDS_TOTAL, stream>>>(xswz, hswz, Wih, Whh, bih, bhh, hlast);
    fc_logsoftmax<<<B_DIM, 64, 0, stream>>>(hlast, fcw, fcb, out);
}